// Round 8
// baseline (98.232 us; speedup 1.0000x reference)
//
#include <hip/hip_runtime.h>
#include <hip/hip_bf16.h>

// SelfAttention (B=4, C=64, N=4096, CQ=8), fp32 in/out.
// K1 proj (1024 blocks, k-chunked, no spills): Q -> compact bf16 [b][n][8]
//   PRE-SCALED by log2(e); K -> compact bf16 [b][n][8];
//   V -> bf16 TILED [b][m>>5][64c][m&31] (4 KB tiles, dense 1 KB frag loads).
// K2 attn (no LDS in loop, no scratch): 64 queries/block (256 blocks).
//   S^T = Kperm^T*Q via mfma_16x16x32_bf16 where lane q16 loads K row
//   8*(q16>>2)+(q16&3); the row permutation makes the exp'd C-frag IDENTICAL
//   to the PV B-operand frag (O^T = V^T * P^T): zero-instruction C->A.
//   Row-sum l computed by an extra MFMA with A=ones (idle MFMA pipe) instead
//   of VALU adds + shuffles. Register double-buffered K/V prefetch at
//   __launch_bounds__(512,2) (256-VGPR budget -> no spills, unlike R5).
//   Unnormalized exp accumulate (|S|<~20: fp32-safe), lane-local division,
//   m split across 8 waves, two-stage (O,l) LDS reduction (69-f stride).

typedef __attribute__((ext_vector_type(8))) short short8;
typedef __attribute__((ext_vector_type(4))) float f32x4;
typedef __attribute__((ext_vector_type(4))) unsigned uint4v;
typedef unsigned short ushort_t;

#define NSEQ 4096
#define LOG2E 1.4426950408889634f

__device__ __forceinline__ unsigned pk_bf16(float lo, float hi) {
  const unsigned short a = __builtin_bit_cast(unsigned short, __float2bfloat16(lo));
  const unsigned short b = __builtin_bit_cast(unsigned short, __float2bfloat16(hi));
  return (unsigned)a | ((unsigned)b << 16);
}

__global__ __launch_bounds__(256, 4) void proj_kernel(
    const float* __restrict__ x,
    const float* __restrict__ Wq, const float* __restrict__ bq,
    const float* __restrict__ Wk, const float* __restrict__ bk,
    const float* __restrict__ Wv, const float* __restrict__ bv,
    ushort_t* __restrict__ Qb, ushort_t* __restrict__ Kb,
    ushort_t* __restrict__ Vb)
{
  const int tid  = threadIdx.x;
  const int lane = tid & 63;
  const int w    = __builtin_amdgcn_readfirstlane(tid >> 6);
  const int blk  = blockIdx.x;
  const int quarter = blk & 3;
  const int g    = (blk >> 2) & 63;
  const int b    = blk >> 8;
  const int n    = g * 64 + lane;

  const float* xb = x + (size_t)(b * 64) * NSEQ + n;
  const int co0 = quarter * 16 + w * 4;
  const float* w0 = Wv + (co0 + 0) * 64;
  const float* w1 = Wv + (co0 + 1) * 64;
  const float* w2 = Wv + (co0 + 2) * 64;
  const float* w3 = Wv + (co0 + 3) * 64;
  const int p = quarter * 4 + w;              // 0..7 -> q, 8..15 -> k
  const float* wr = (p < 8) ? (Wq + p * 64) : (Wk + (p - 8) * 64);
  float a0 = bv[co0 + 0], a1 = bv[co0 + 1], a2 = bv[co0 + 2], a3 = bv[co0 + 3];
  float aq = (p < 8) ? bq[p] : bk[p - 8];

  // k-chunked streaming: few live VGPRs, weight reads are s_loads
#pragma unroll
  for (int kc = 0; kc < 64; kc += 8) {
    float xv[8];
#pragma unroll
    for (int i = 0; i < 8; ++i) xv[i] = xb[(size_t)(kc + i) * NSEQ];
#pragma unroll
    for (int i = 0; i < 8; ++i) {
      const float xk = xv[i];
      a0 += w0[kc + i] * xk;
      a1 += w1[kc + i] * xk;
      a2 += w2[kc + i] * xk;
      a3 += w3[kc + i] * xk;
      aq += wr[kc + i] * xk;
    }
  }

  // V tiled store: tile (b, n>>5), row co, col n&31
  ushort_t* vt = Vb + ((size_t)(b * 128 + (n >> 5)) * 64 + co0) * 32 + (n & 31);
  vt[0]  = __builtin_bit_cast(ushort_t, __float2bfloat16(a0));
  vt[32] = __builtin_bit_cast(ushort_t, __float2bfloat16(a1));
  vt[64] = __builtin_bit_cast(ushort_t, __float2bfloat16(a2));
  vt[96] = __builtin_bit_cast(ushort_t, __float2bfloat16(a3));

  // Q pre-scaled by log2(e) so attn's exp is a bare v_exp_f32
  if (p < 8) aq *= LOG2E;
  ushort_t* qk = ((p < 8) ? Qb : Kb) + ((size_t)(b * NSEQ + n)) * 8 + (p & 7);
  *qk = __builtin_bit_cast(ushort_t, __float2bfloat16(aq));
}

__global__ __launch_bounds__(512, 2) void attn_kernel(
    const ushort_t* __restrict__ Qb, const ushort_t* __restrict__ Kb,
    const ushort_t* __restrict__ Vb, const float* __restrict__ x,
    const float* __restrict__ gamma, float* __restrict__ out)
{
  __shared__ float buf[4][64][69];   // staged (O,l) reduction, 70.7 KB

  const int tid  = threadIdx.x;
  const int wave = __builtin_amdgcn_readfirstlane(tid >> 6);   // 0..7
  const int lane = tid & 63;
  const int q16  = lane & 15;
  const int quad = lane >> 4;
  const int blk  = blockIdx.x;
  const int b    = blk >> 6;
  const int n0   = (blk & 63) << 6;    // block's 64 queries
  const int mbase = wave << 9;         // this wave's 512-m range

  // Q B-frags for 4 q-subtiles (k>=8 zeroed so compact K loads raw)
  const short8 z8 = {0, 0, 0, 0, 0, 0, 0, 0};
  short8 qf[4];
#pragma unroll
  for (int qt = 0; qt < 4; ++qt) {
    qf[qt] = *(const short8*)(Qb + ((size_t)(b * NSEQ + n0 + qt * 16 + q16)) * 8);
    if (quad != 0) qf[qt] = z8;
  }

  // A = ones (bf16 1.0): extra PV MFMA gives D[c][n] = sum_m P[m][n] = l
  const short one_bf = (short)0x3F80;
  const short8 ones = {one_bf, one_bf, one_bf, one_bf,
                       one_bf, one_bf, one_bf, one_bf};

  // K A-frag with the row permutation: lane q16 -> row 8*(q16>>2)+(q16&3)
  // => exp'd S^T C-frag IS the PV B-frag (k = 8*quad+j <-> m = 8*quad+j).
  const int mperm = 8 * (q16 >> 2) + (q16 & 3);
  const char* kbase = (const char*)(Kb + ((size_t)(b * NSEQ + mbase + mperm)) * 8);
  // V A-frag (V^T): A[row=c=q16][k=m=quad*8+j] from tiled [64c][32m] 4KB tiles
  const char* vbase = (const char*)(Vb + ((size_t)(b * 128 + (mbase >> 5)) * 64) * 32)
                      + q16 * 64 + quad * 16;

  // accumulators: acc[qt][cf] = D[c=16cf+4quad+r][n=n0+16qt+q16]
  f32x4 acc[4][4];
  f32x4 lacc[4];
#pragma unroll
  for (int qt = 0; qt < 4; ++qt) {
    lacc[qt] = (f32x4){0.f, 0.f, 0.f, 0.f};
#pragma unroll
    for (int cf = 0; cf < 4; ++cf) acc[qt][cf] = (f32x4){0.f, 0.f, 0.f, 0.f};
  }

  // register double-buffered K/V tiles (safe at 256-VGPR budget)
  short8 kf0 = *(const short8*)(kbase);
  short8 kf1 = *(const short8*)(kbase + 64);
  short8 vf0 = *(const short8*)(vbase);
  short8 vf1 = *(const short8*)(vbase + 1024);
  short8 vf2 = *(const short8*)(vbase + 2048);
  short8 vf3 = *(const short8*)(vbase + 3072);

#pragma unroll 2
  for (int t = 0; t < 16; ++t) {
    const int tn = (t + 1 < 16) ? (t + 1) : 15;   // clamped prefetch
    const char* kp = kbase + (size_t)tn * 512;    // 32 K rows * 16 B
    const char* vp = vbase + (size_t)tn * 4096;   // next 4 KB V tile
    const short8 nk0 = *(const short8*)(kp);
    const short8 nk1 = *(const short8*)(kp + 64);
    const short8 nv0 = *(const short8*)(vp);
    const short8 nv1 = *(const short8*)(vp + 1024);
    const short8 nv2 = *(const short8*)(vp + 2048);
    const short8 nv3 = *(const short8*)(vp + 3072);

#pragma unroll
    for (int qt = 0; qt < 4; ++qt) {
      // S^T in log2 domain (Q pre-scaled): D[mperm][n]
      const f32x4 z = {0.f, 0.f, 0.f, 0.f};
      f32x4 s0 = __builtin_amdgcn_mfma_f32_16x16x32_bf16(kf0, qf[qt], z, 0, 0, 0);
      f32x4 s1 = __builtin_amdgcn_mfma_f32_16x16x32_bf16(kf1, qf[qt], z, 0, 0, 0);

      // unnormalized numerators; lane (quad, n) holds m = 8*quad..8*quad+7
      const float p0 = __builtin_amdgcn_exp2f(s0[0]);
      const float p1 = __builtin_amdgcn_exp2f(s0[1]);
      const float p2 = __builtin_amdgcn_exp2f(s0[2]);
      const float p3 = __builtin_amdgcn_exp2f(s0[3]);
      const float p4 = __builtin_amdgcn_exp2f(s1[0]);
      const float p5 = __builtin_amdgcn_exp2f(s1[1]);
      const float p6 = __builtin_amdgcn_exp2f(s1[2]);
      const float p7 = __builtin_amdgcn_exp2f(s1[3]);

      // pack pairs: register bit_cast; result IS the PV B-frag B[k=8q+j][n]
      const uint4v u = {pk_bf16(p0, p1), pk_bf16(p2, p3),
                        pk_bf16(p4, p5), pk_bf16(p6, p7)};
      const short8 pf = __builtin_bit_cast(short8, u);

      // O^T[c][n] += V^T[c][m] * P^T[m][n]; l via ones-A MFMA (idle pipe)
      acc[qt][0] = __builtin_amdgcn_mfma_f32_16x16x32_bf16(vf0, pf, acc[qt][0], 0, 0, 0);
      acc[qt][1] = __builtin_amdgcn_mfma_f32_16x16x32_bf16(vf1, pf, acc[qt][1], 0, 0, 0);
      acc[qt][2] = __builtin_amdgcn_mfma_f32_16x16x32_bf16(vf2, pf, acc[qt][2], 0, 0, 0);
      acc[qt][3] = __builtin_amdgcn_mfma_f32_16x16x32_bf16(vf3, pf, acc[qt][3], 0, 0, 0);
      lacc[qt]   = __builtin_amdgcn_mfma_f32_16x16x32_bf16(ones, pf, lacc[qt], 0, 0, 0);
    }

    kf0 = nk0; kf1 = nk1;
    vf0 = nv0; vf1 = nv1; vf2 = nv2; vf3 = nv3;
  }

  // l (this wave's m-range) is lane-local: lacc[qt][r] all equal l(n=n0+16qt+q16)
  float l[4];
#pragma unroll
  for (int qt = 0; qt < 4; ++qt) l[qt] = lacc[qt][0];

  // two-stage cross-wave (O,l) reduction: 8 waves -> 4 -> gather
  if (wave >= 4) {
    float* d = &buf[wave - 4][lane][0];
#pragma unroll
    for (int qt = 0; qt < 4; ++qt) {
#pragma unroll
      for (int cf = 0; cf < 4; ++cf)
#pragma unroll
        for (int r = 0; r < 4; ++r) d[qt * 16 + cf * 4 + r] = acc[qt][cf][r];
      d[64 + qt] = l[qt];
    }
  }
  __syncthreads();
  if (wave < 4) {
    float* d = &buf[wave][lane][0];
#pragma unroll
    for (int qt = 0; qt < 4; ++qt) {
#pragma unroll
      for (int cf = 0; cf < 4; ++cf)
#pragma unroll
        for (int r = 0; r < 4; ++r) {
          acc[qt][cf][r] += d[qt * 16 + cf * 4 + r];
          d[qt * 16 + cf * 4 + r] = acc[qt][cf][r];
        }
      l[qt] += d[64 + qt];
      d[64 + qt] = l[qt];
    }
  }
  __syncthreads();

  // gather: wave -> qt = wave>>1, cg pair = 2*(wave&1)+{0,1};
  // lane (quad, q16) owns c = 16cg+4quad+r, n = n0+16qt+q16
  const int qt = wave >> 1;
  const int cg0 = (wave & 1) * 2;
  float lt = 0.f;
#pragma unroll
  for (int w2 = 0; w2 < 4; ++w2) lt += buf[w2][lane][64 + qt];
  const float ginv = gamma[0] / lt;
  const int nn = n0 + qt * 16 + q16;

#pragma unroll
  for (int h = 0; h < 2; ++h) {
    const int cg = cg0 + h;
    float fr[4] = {0.f, 0.f, 0.f, 0.f};
#pragma unroll
    for (int w2 = 0; w2 < 4; ++w2)
#pragma unroll
      for (int r = 0; r < 4; ++r) fr[r] += buf[w2][lane][qt * 16 + cg * 4 + r];
#pragma unroll
    for (int r = 0; r < 4; ++r) {
      const int c = cg * 16 + quad * 4 + r;
      const size_t idx = ((size_t)(b * 64 + c)) * NSEQ + nn;
      out[idx] = fr[r] * ginv + x[idx];
    }
  }
}

extern "C" void kernel_launch(void* const* d_in, const int* in_sizes, int n_in,
                              void* d_out, int out_size, void* d_ws, size_t ws_size,
                              hipStream_t stream) {
  (void)in_sizes; (void)n_in; (void)out_size; (void)ws_size;
  const float* x     = (const float*)d_in[0];
  const float* Wq    = (const float*)d_in[1];
  const float* bq    = (const float*)d_in[2];
  const float* Wk    = (const float*)d_in[3];
  const float* bk    = (const float*)d_in[4];
  const float* Wv    = (const float*)d_in[5];
  const float* bv    = (const float*)d_in[6];
  const float* gamma = (const float*)d_in[7];
  float* out = (float*)d_out;

  // workspace: Qb 256 KB | Kb 256 KB | Vb(tiled) 2 MB
  ushort_t* Qb = (ushort_t*)d_ws;
  ushort_t* Kb = (ushort_t*)((char*)d_ws + (256u << 10));
  ushort_t* Vb = (ushort_t*)((char*)d_ws + (512u << 10));

  hipLaunchKernelGGL(proj_kernel, dim3(1024), dim3(256), 0, stream,
                     x, Wq, bq, Wk, bk, Wv, bv, Qb, Kb, Vb);
  hipLaunchKernelGGL(attn_kernel, dim3(256), dim3(512), 0, stream,
                     Qb, Kb, Vb, x, gamma, out);
}

// Round 9
// 95.196 us; speedup vs baseline: 1.0319x; 1.0319x over previous
//
#include <hip/hip_runtime.h>
#include <hip/hip_bf16.h>

// SelfAttention (B=4, C=64, N=4096, CQ=8), fp32 in/out.
// == R7 configuration (best measured: 95.2 us) ==
// K1 proj (1024 blocks, k-chunked, no spills): Q -> compact bf16 [b][n][8]
//   PRE-SCALED by log2(e); K -> compact bf16 [b][n][8];
//   V -> bf16 TILED [b][m>>5][64c][m&31] (4 KB tiles, dense 1 KB frag loads).
// K2 attn (no LDS in loop, no scratch, no manual prefetch): 64 queries/block
//   (256 blocks). S^T = Kperm^T*Q via mfma_16x16x32_bf16 where lane q16 loads
//   K row 8*(q16>>2)+(q16&3); this row permutation makes the exp'd C-frag
//   IDENTICAL to the PV B-operand frag (O^T = V^T * P^T): zero-instruction
//   C->A transform. bit_cast only (no unions -> no scratch). Unnormalized
//   exp accumulate (|S|<~20), lane-local row-sum division, m split across
//   8 waves, two-stage (O,l) LDS reduction (69-float stride, conflict-free).
// Session lessons baked in: no explicit prefetch regs (regressed twice:
//   R5 spills at (512,4), R8 pressure at (512,2)); no ones-MFMA for l
//   (MFMA issue cost >= VALU saved); VALU adds for l + 2 shuffles is cheapest.

typedef __attribute__((ext_vector_type(8))) short short8;
typedef __attribute__((ext_vector_type(4))) float f32x4;
typedef __attribute__((ext_vector_type(4))) unsigned uint4v;
typedef unsigned short ushort_t;

#define NSEQ 4096
#define LOG2E 1.4426950408889634f

__device__ __forceinline__ unsigned pk_bf16(float lo, float hi) {
  const unsigned short a = __builtin_bit_cast(unsigned short, __float2bfloat16(lo));
  const unsigned short b = __builtin_bit_cast(unsigned short, __float2bfloat16(hi));
  return (unsigned)a | ((unsigned)b << 16);
}

__global__ __launch_bounds__(256, 4) void proj_kernel(
    const float* __restrict__ x,
    const float* __restrict__ Wq, const float* __restrict__ bq,
    const float* __restrict__ Wk, const float* __restrict__ bk,
    const float* __restrict__ Wv, const float* __restrict__ bv,
    ushort_t* __restrict__ Qb, ushort_t* __restrict__ Kb,
    ushort_t* __restrict__ Vb)
{
  const int tid  = threadIdx.x;
  const int lane = tid & 63;
  const int w    = __builtin_amdgcn_readfirstlane(tid >> 6);
  const int blk  = blockIdx.x;
  const int quarter = blk & 3;
  const int g    = (blk >> 2) & 63;
  const int b    = blk >> 8;
  const int n    = g * 64 + lane;

  const float* xb = x + (size_t)(b * 64) * NSEQ + n;
  const int co0 = quarter * 16 + w * 4;
  const float* w0 = Wv + (co0 + 0) * 64;
  const float* w1 = Wv + (co0 + 1) * 64;
  const float* w2 = Wv + (co0 + 2) * 64;
  const float* w3 = Wv + (co0 + 3) * 64;
  const int p = quarter * 4 + w;              // 0..7 -> q, 8..15 -> k
  const float* wr = (p < 8) ? (Wq + p * 64) : (Wk + (p - 8) * 64);
  float a0 = bv[co0 + 0], a1 = bv[co0 + 1], a2 = bv[co0 + 2], a3 = bv[co0 + 3];
  float aq = (p < 8) ? bq[p] : bk[p - 8];

  // k-chunked streaming: few live VGPRs, weight reads are s_loads
#pragma unroll
  for (int kc = 0; kc < 64; kc += 8) {
    float xv[8];
#pragma unroll
    for (int i = 0; i < 8; ++i) xv[i] = xb[(size_t)(kc + i) * NSEQ];
#pragma unroll
    for (int i = 0; i < 8; ++i) {
      const float xk = xv[i];
      a0 += w0[kc + i] * xk;
      a1 += w1[kc + i] * xk;
      a2 += w2[kc + i] * xk;
      a3 += w3[kc + i] * xk;
      aq += wr[kc + i] * xk;
    }
  }

  // V tiled store: tile (b, n>>5), row co, col n&31
  ushort_t* vt = Vb + ((size_t)(b * 128 + (n >> 5)) * 64 + co0) * 32 + (n & 31);
  vt[0]  = __builtin_bit_cast(ushort_t, __float2bfloat16(a0));
  vt[32] = __builtin_bit_cast(ushort_t, __float2bfloat16(a1));
  vt[64] = __builtin_bit_cast(ushort_t, __float2bfloat16(a2));
  vt[96] = __builtin_bit_cast(ushort_t, __float2bfloat16(a3));

  // Q pre-scaled by log2(e) so attn's exp is a bare v_exp_f32
  if (p < 8) aq *= LOG2E;
  ushort_t* qk = ((p < 8) ? Qb : Kb) + ((size_t)(b * NSEQ + n)) * 8 + (p & 7);
  *qk = __builtin_bit_cast(ushort_t, __float2bfloat16(aq));
}

__global__ __launch_bounds__(512, 2) void attn_kernel(
    const ushort_t* __restrict__ Qb, const ushort_t* __restrict__ Kb,
    const ushort_t* __restrict__ Vb, const float* __restrict__ x,
    const float* __restrict__ gamma, float* __restrict__ out)
{
  __shared__ float buf[4][64][69];   // staged (O,l) reduction, 70.7 KB

  const int tid  = threadIdx.x;
  const int wave = __builtin_amdgcn_readfirstlane(tid >> 6);   // 0..7
  const int lane = tid & 63;
  const int q16  = lane & 15;
  const int quad = lane >> 4;
  const int blk  = blockIdx.x;
  const int b    = blk >> 6;
  const int n0   = (blk & 63) << 6;    // block's 64 queries
  const int mbase = wave << 9;         // this wave's 512-m range

  // Q B-frags for 4 q-subtiles (k>=8 zeroed so compact K loads raw)
  const short8 z8 = {0, 0, 0, 0, 0, 0, 0, 0};
  short8 qf[4];
#pragma unroll
  for (int qt = 0; qt < 4; ++qt) {
    qf[qt] = *(const short8*)(Qb + ((size_t)(b * NSEQ + n0 + qt * 16 + q16)) * 8);
    if (quad != 0) qf[qt] = z8;
  }

  // K A-frag with the row permutation: lane q16 -> row 8*(q16>>2)+(q16&3)
  // => exp'd S^T C-frag IS the PV B-frag (k = 8*quad+j <-> m = 8*quad+j).
  const int mperm = 8 * (q16 >> 2) + (q16 & 3);
  const char* kbase = (const char*)(Kb + ((size_t)(b * NSEQ + mbase + mperm)) * 8);
  // V A-frag (V^T): A[row=c=q16][k=m=quad*8+j] from tiled [64c][32m] 4KB tiles
  const char* vbase = (const char*)(Vb + ((size_t)(b * 128 + (mbase >> 5)) * 64) * 32)
                      + q16 * 64 + quad * 16;

  // accumulators: acc[qt][cf] = D[c=16cf+4quad+r][n=n0+16qt+q16]
  f32x4 acc[4][4];
#pragma unroll
  for (int qt = 0; qt < 4; ++qt)
#pragma unroll
    for (int cf = 0; cf < 4; ++cf) acc[qt][cf] = (f32x4){0.f, 0.f, 0.f, 0.f};
  float l[4] = {0.f, 0.f, 0.f, 0.f};

#pragma unroll 1
  for (int t = 0; t < 16; ++t) {
    const char* kp = kbase + (size_t)t * 512;    // 32 K rows * 16 B
    const char* vp = vbase + (size_t)t * 4096;   // 4 KB V tile
    const short8 kf0 = *(const short8*)(kp);         // rows {8q..8q+3}
    const short8 kf1 = *(const short8*)(kp + 64);    // rows {8q+4..8q+7}
    const short8 vf0 = *(const short8*)(vp);
    const short8 vf1 = *(const short8*)(vp + 1024);
    const short8 vf2 = *(const short8*)(vp + 2048);
    const short8 vf3 = *(const short8*)(vp + 3072);

#pragma unroll
    for (int qt = 0; qt < 4; ++qt) {
      // S^T in log2 domain (Q pre-scaled): D[mperm][n]
      const f32x4 z = {0.f, 0.f, 0.f, 0.f};
      f32x4 s0 = __builtin_amdgcn_mfma_f32_16x16x32_bf16(kf0, qf[qt], z, 0, 0, 0);
      f32x4 s1 = __builtin_amdgcn_mfma_f32_16x16x32_bf16(kf1, qf[qt], z, 0, 0, 0);

      // unnormalized numerators; lane (quad, n) holds m = 8*quad..8*quad+7
      const float p0 = __builtin_amdgcn_exp2f(s0[0]);
      const float p1 = __builtin_amdgcn_exp2f(s0[1]);
      const float p2 = __builtin_amdgcn_exp2f(s0[2]);
      const float p3 = __builtin_amdgcn_exp2f(s0[3]);
      const float p4 = __builtin_amdgcn_exp2f(s1[0]);
      const float p5 = __builtin_amdgcn_exp2f(s1[1]);
      const float p6 = __builtin_amdgcn_exp2f(s1[2]);
      const float p7 = __builtin_amdgcn_exp2f(s1[3]);
      l[qt] += ((p0 + p1) + (p2 + p3)) + ((p4 + p5) + (p6 + p7));

      // pack pairs: register bit_cast; result IS the PV B-frag B[k=8q+j][n]
      const uint4v u = {pk_bf16(p0, p1), pk_bf16(p2, p3),
                        pk_bf16(p4, p5), pk_bf16(p6, p7)};
      const short8 pf = __builtin_bit_cast(short8, u);

      // O^T[c][n] += V^T[c][m] * P^T[m][n]
      acc[qt][0] = __builtin_amdgcn_mfma_f32_16x16x32_bf16(vf0, pf, acc[qt][0], 0, 0, 0);
      acc[qt][1] = __builtin_amdgcn_mfma_f32_16x16x32_bf16(vf1, pf, acc[qt][1], 0, 0, 0);
      acc[qt][2] = __builtin_amdgcn_mfma_f32_16x16x32_bf16(vf2, pf, acc[qt][2], 0, 0, 0);
      acc[qt][3] = __builtin_amdgcn_mfma_f32_16x16x32_bf16(vf3, pf, acc[qt][3], 0, 0, 0);
    }
  }

  // full (this wave's m-range) row sums; lane-local for n = n0+16qt+q16
#pragma unroll
  for (int qt = 0; qt < 4; ++qt) {
    l[qt] += __shfl_xor(l[qt], 16);
    l[qt] += __shfl_xor(l[qt], 32);
  }

  // two-stage cross-wave (O,l) reduction: 8 waves -> 4 -> gather
  if (wave >= 4) {
    float* d = &buf[wave - 4][lane][0];
#pragma unroll
    for (int qt = 0; qt < 4; ++qt) {
#pragma unroll
      for (int cf = 0; cf < 4; ++cf)
#pragma unroll
        for (int r = 0; r < 4; ++r) d[qt * 16 + cf * 4 + r] = acc[qt][cf][r];
      d[64 + qt] = l[qt];
    }
  }
  __syncthreads();
  if (wave < 4) {
    float* d = &buf[wave][lane][0];
#pragma unroll
    for (int qt = 0; qt < 4; ++qt) {
#pragma unroll
      for (int cf = 0; cf < 4; ++cf)
#pragma unroll
        for (int r = 0; r < 4; ++r) {
          acc[qt][cf][r] += d[qt * 16 + cf * 4 + r];
          d[qt * 16 + cf * 4 + r] = acc[qt][cf][r];
        }
      l[qt] += d[64 + qt];
      d[64 + qt] = l[qt];
    }
  }
  __syncthreads();

  // gather: wave -> qt = wave>>1, cg pair = 2*(wave&1)+{0,1};
  // lane (quad, q16) owns c = 16cg+4quad+r, n = n0+16qt+q16
  const int qt = wave >> 1;
  const int cg0 = (wave & 1) * 2;
  float lt = 0.f;
#pragma unroll
  for (int w2 = 0; w2 < 4; ++w2) lt += buf[w2][lane][64 + qt];
  const float ginv = gamma[0] / lt;
  const int nn = n0 + qt * 16 + q16;

#pragma unroll
  for (int h = 0; h < 2; ++h) {
    const int cg = cg0 + h;
    float fr[4] = {0.f, 0.f, 0.f, 0.f};
#pragma unroll
    for (int w2 = 0; w2 < 4; ++w2)
#pragma unroll
      for (int r = 0; r < 4; ++r) fr[r] += buf[w2][lane][qt * 16 + cg * 4 + r];
#pragma unroll
    for (int r = 0; r < 4; ++r) {
      const int c = cg * 16 + quad * 4 + r;
      const size_t idx = ((size_t)(b * 64 + c)) * NSEQ + nn;
      out[idx] = fr[r] * ginv + x[idx];
    }
  }
}

extern "C" void kernel_launch(void* const* d_in, const int* in_sizes, int n_in,
                              void* d_out, int out_size, void* d_ws, size_t ws_size,
                              hipStream_t stream) {
  (void)in_sizes; (void)n_in; (void)out_size; (void)ws_size;
  const float* x     = (const float*)d_in[0];
  const float* Wq    = (const float*)d_in[1];
  const float* bq    = (const float*)d_in[2];
  const float* Wk    = (const float*)d_in[3];
  const float* bk    = (const float*)d_in[4];
  const float* Wv    = (const float*)d_in[5];
  const float* bv    = (const float*)d_in[6];
  const float* gamma = (const float*)d_in[7];
  float* out = (float*)d_out;

  // workspace: Qb 256 KB | Kb 256 KB | Vb(tiled) 2 MB
  ushort_t* Qb = (ushort_t*)d_ws;
  ushort_t* Kb = (ushort_t*)((char*)d_ws + (256u << 10));
  ushort_t* Vb = (ushort_t*)((char*)d_ws + (512u << 10));

  hipLaunchKernelGGL(proj_kernel, dim3(1024), dim3(256), 0, stream,
                     x, Wq, bq, Wk, bk, Wv, bv, Qb, Kb, Vb);
  hipLaunchKernelGGL(attn_kernel, dim3(256), dim3(512), 0, stream,
                     Qb, Kb, Vb, x, gamma, out);
}